// Round 1
// baseline (140.185 us; speedup 1.0000x reference)
//
#include <hip/hip_runtime.h>
#include <hip/hip_bf16.h>
#include <stdint.h>

// Problem constants
#define BDIM 4096
#define CDIM 10000
#define DDIM 512
#define CPAD 10112  // 79 * 128, padded N so GEMM loads need no guards

typedef __bf16 bf16_t;
typedef __attribute__((ext_vector_type(2))) __bf16 bf16x2;
typedef __attribute__((ext_vector_type(8))) __bf16 bf16x8;
typedef __attribute__((ext_vector_type(4))) float f32x4;

__device__ __forceinline__ void gl_lds16(const void* g, void* s) {
  // async global->LDS, 16B per lane; LDS dest = wave-uniform base + lane*16
  __builtin_amdgcn_global_load_lds(
      (const __attribute__((address_space(1))) void*)g,
      (__attribute__((address_space(3))) void*)s, 16, 0, 0);
}

// --- prep feat: fp32 -> bf16, and per-row sum of squares (fp32 exact) ---
__global__ __launch_bounds__(256) void prep_feat(
    const float* __restrict__ feat, bf16_t* __restrict__ fb,
    float* __restrict__ f2) {
  const int row = blockIdx.x;
  const int t = threadIdx.x;
  const float2 v = ((const float2*)(feat + (size_t)row * DDIM))[t];
  bf16x2 o;
  o.x = (__bf16)v.x;
  o.y = (__bf16)v.y;
  ((bf16x2*)fb)[(size_t)row * (DDIM / 2) + t] = o;
  float ss = v.x * v.x + v.y * v.y;
#pragma unroll
  for (int off = 32; off > 0; off >>= 1) ss += __shfl_down(ss, off);
  __shared__ float red[4];
  if ((t & 63) == 0) red[t >> 6] = ss;
  __syncthreads();
  if (t == 0) f2[row] = red[0] + red[1] + red[2] + red[3];
}

// --- prep weights: fp32 -> bf16 (zero-padded rows [10000,10112)),
//     per-row sum of squares, and fp32 passthrough copy into d_out ---
__global__ __launch_bounds__(256) void prep_w(
    const float* __restrict__ w, bf16_t* __restrict__ wb,
    float* __restrict__ w2, float* __restrict__ wout) {
  const int row = blockIdx.x;
  const int t = threadIdx.x;
  __shared__ float red[4];
  if (row < CDIM) {
    const float2 v = ((const float2*)(w + (size_t)row * DDIM))[t];
    ((float2*)(wout + (size_t)row * DDIM))[t] = v;  // exact passthrough
    bf16x2 o;
    o.x = (__bf16)v.x;
    o.y = (__bf16)v.y;
    ((bf16x2*)wb)[(size_t)row * (DDIM / 2) + t] = o;
    float ss = v.x * v.x + v.y * v.y;
#pragma unroll
    for (int off = 32; off > 0; off >>= 1) ss += __shfl_down(ss, off);
    if ((t & 63) == 0) red[t >> 6] = ss;
    __syncthreads();
    if (t == 0) w2[row] = red[0] + red[1] + red[2] + red[3];
  } else {
    bf16x2 z;
    z.x = (__bf16)0.0f;
    z.y = (__bf16)0.0f;
    ((bf16x2*)wb)[(size_t)row * (DDIM / 2) + t] = z;
    if (t == 0) w2[row] = 0.0f;
  }
}

// --- main GEMM + RBF epilogue ---
// 128x128 tile, BK=32, 256 threads = 4 waves (2x2), each wave 64x64 via
// 4x4 frags of mfma_f32_16x16x32_bf16. Both operands are [rows][K] row-major.
__global__ __launch_bounds__(256) void rbf_gemm(
    const bf16_t* __restrict__ A,   // [4096][512] bf16
    const bf16_t* __restrict__ Bw,  // [10112][512] bf16 (padded)
    const float* __restrict__ f2g, const float* __restrict__ w2g,
    float* __restrict__ out) {
  __shared__ bf16_t At[128 * 32];
  __shared__ bf16_t Bt[128 * 32];
  __shared__ float f2s[128];
  __shared__ float w2s[128];

  const int bn = blockIdx.x;  // 0..78 (N tiles)
  const int bm = blockIdx.y;  // 0..31 (M tiles)
  const int t = threadIdx.x;
  const int lane = t & 63;

  if (t < 128)
    f2s[t] = f2g[bm * 128 + t];
  else
    w2s[t - 128] = w2g[bn * 128 + (t - 128)];

  // staging addressing: 4 threads x 16B per 32-elem row; 64 rows per call
  const int sr = t >> 2;
  const int sc = (t & 3) * 8;
  const bf16_t* ga0 = A + (size_t)(bm * 128 + sr) * DDIM + sc;
  const bf16_t* ga1 = ga0 + (size_t)64 * DDIM;
  const bf16_t* gb0 = Bw + (size_t)(bn * 128 + sr) * DDIM + sc;
  const bf16_t* gb1 = gb0 + (size_t)64 * DDIM;
  bf16_t* sa = At + t * 8;  // linear: wave base + lane*16B
  bf16_t* sb = Bt + t * 8;

  const int wv = t >> 6;
  const int wm = (wv >> 1) * 64;
  const int wn = (wv & 1) * 64;
  const int fr = lane & 15;
  const int k8 = (lane >> 4) * 8;

  f32x4 acc[4][4];
#pragma unroll
  for (int i = 0; i < 4; ++i)
#pragma unroll
    for (int j = 0; j < 4; ++j) acc[i][j] = (f32x4){0.f, 0.f, 0.f, 0.f};

  for (int kt = 0; kt < DDIM / 32; ++kt) {
    const int k0 = kt * 32;
    gl_lds16(ga0 + k0, sa);
    gl_lds16(ga1 + k0, sa + 64 * 32);
    gl_lds16(gb0 + k0, sb);
    gl_lds16(gb1 + k0, sb + 64 * 32);
    __syncthreads();
    bf16x8 af[4], bfr[4];
#pragma unroll
    for (int mi = 0; mi < 4; ++mi)
      af[mi] = *(const bf16x8*)(At + (wm + mi * 16 + fr) * 32 + k8);
#pragma unroll
    for (int ni = 0; ni < 4; ++ni)
      bfr[ni] = *(const bf16x8*)(Bt + (wn + ni * 16 + fr) * 32 + k8);
#pragma unroll
    for (int mi = 0; mi < 4; ++mi)
#pragma unroll
      for (int ni = 0; ni < 4; ++ni)
        acc[mi][ni] = __builtin_amdgcn_mfma_f32_16x16x32_bf16(
            af[mi], bfr[ni], acc[mi][ni], 0, 0, 0);
    __syncthreads();
  }

  // epilogue: logit = exp(-0.01 * max(f2 + w2 - 2*cross, 0)) to both segments
  const size_t BC = (size_t)BDIM * CDIM;
#pragma unroll
  for (int mi = 0; mi < 4; ++mi) {
#pragma unroll
    for (int j = 0; j < 4; ++j) {
      const int rl = wm + mi * 16 + (lane >> 4) * 4 + j;
      const int grow = bm * 128 + rl;
      const float frow = f2s[rl];
      float* orow = out + (size_t)grow * CDIM;
#pragma unroll
      for (int ni = 0; ni < 4; ++ni) {
        const int cl = wn + ni * 16 + fr;
        const int gcol = bn * 128 + cl;
        if (gcol < CDIM) {
          float m = frow + w2s[cl] - 2.0f * acc[mi][ni][j];
          m = fmaxf(m, 0.0f);
          const float lg = __expf(-0.01f * m);
          orow[gcol] = lg;
          orow[BC + gcol] = lg;
        }
      }
    }
  }
}

extern "C" void kernel_launch(void* const* d_in, const int* in_sizes, int n_in,
                              void* d_out, int out_size, void* d_ws,
                              size_t ws_size, hipStream_t stream) {
  const float* feat = (const float*)d_in[0];
  // d_in[1] = label (int64) — unused by the reference math
  const float* w = (const float*)d_in[2];
  float* out = (float*)d_out;

  char* ws = (char*)d_ws;
  bf16_t* fb = (bf16_t*)ws;                        // 4096*512*2  = 4,194,304 B
  bf16_t* wb = (bf16_t*)(ws + 4194304);            // 10112*512*2 = 10,354,688 B
  float* f2 = (float*)(ws + 4194304 + 10354688);   // 16,384 B
  float* w2 = (float*)(ws + 4194304 + 10354688 + 16384);  // 40,448 B

  float* wout = out + (size_t)2 * BDIM * CDIM;  // weights passthrough segment

  prep_feat<<<BDIM, 256, 0, stream>>>(feat, fb, f2);
  prep_w<<<CPAD, 256, 0, stream>>>(w, wb, w2, wout);
  rbf_gemm<<<dim3(79, 32), 256, 0, stream>>>(fb, wb, f2, w2, out);
}

// Round 2
// 138.586 us; speedup vs baseline: 1.0115x; 1.0115x over previous
//
#include <hip/hip_runtime.h>
#include <hip/hip_bf16.h>
#include <stdint.h>

// Problem constants
#define BDIM 4096
#define CDIM 10000
#define DDIM 512
#define CPAD 10112  // 79 * 128, padded N so GEMM loads need no guards

typedef __bf16 bf16_t;
typedef __attribute__((ext_vector_type(2))) __bf16 bf16x2;
typedef __attribute__((ext_vector_type(8))) __bf16 bf16x8;
typedef __attribute__((ext_vector_type(4))) float f32x4;

__device__ __forceinline__ void gl_lds16(const void* g, void* s) {
  // async global->LDS, 16B per lane; LDS dest = wave-uniform base + lane*16
  __builtin_amdgcn_global_load_lds(
      (const __attribute__((address_space(1))) void*)g,
      (__attribute__((address_space(3))) void*)s, 16, 0, 0);
}

// --- prep feat: fp32 -> bf16, and per-row sum of squares (fp32 exact) ---
__global__ __launch_bounds__(256) void prep_feat(
    const float* __restrict__ feat, bf16_t* __restrict__ fb,
    float* __restrict__ f2) {
  const int row = blockIdx.x;
  const int t = threadIdx.x;
  const float2 v = ((const float2*)(feat + (size_t)row * DDIM))[t];
  bf16x2 o;
  o.x = (__bf16)v.x;
  o.y = (__bf16)v.y;
  ((bf16x2*)fb)[(size_t)row * (DDIM / 2) + t] = o;
  float ss = v.x * v.x + v.y * v.y;
#pragma unroll
  for (int off = 32; off > 0; off >>= 1) ss += __shfl_down(ss, off);
  __shared__ float red[4];
  if ((t & 63) == 0) red[t >> 6] = ss;
  __syncthreads();
  if (t == 0) f2[row] = red[0] + red[1] + red[2] + red[3];
}

// --- prep weights: fp32 -> bf16 (zero-padded rows [10000,10112)),
//     per-row sum of squares, and fp32 passthrough copy into d_out ---
__global__ __launch_bounds__(256) void prep_w(
    const float* __restrict__ w, bf16_t* __restrict__ wb,
    float* __restrict__ w2, float* __restrict__ wout) {
  const int row = blockIdx.x;
  const int t = threadIdx.x;
  __shared__ float red[4];
  if (row < CDIM) {
    const float2 v = ((const float2*)(w + (size_t)row * DDIM))[t];
    ((float2*)(wout + (size_t)row * DDIM))[t] = v;  // exact passthrough
    bf16x2 o;
    o.x = (__bf16)v.x;
    o.y = (__bf16)v.y;
    ((bf16x2*)wb)[(size_t)row * (DDIM / 2) + t] = o;
    float ss = v.x * v.x + v.y * v.y;
#pragma unroll
    for (int off = 32; off > 0; off >>= 1) ss += __shfl_down(ss, off);
    if ((t & 63) == 0) red[t >> 6] = ss;
    __syncthreads();
    if (t == 0) w2[row] = red[0] + red[1] + red[2] + red[3];
  } else {
    bf16x2 z;
    z.x = (__bf16)0.0f;
    z.y = (__bf16)0.0f;
    ((bf16x2*)wb)[(size_t)row * (DDIM / 2) + t] = z;
    if (t == 0) w2[row] = 0.0f;
  }
}

// --- main GEMM + RBF epilogue ---
// 128x128 tile, BK=32, 256 threads = 4 waves (2x2), each wave 64x64 via
// 4x4 frags of mfma_f32_16x16x32_bf16. OPERAND-SWAPPED: mfma(wfrag, ffrag)
// so D rows = weight cols, D cols = feat rows -> per-lane 4 consecutive
// output columns of one feat row -> float4 stores.
__global__ __launch_bounds__(256) void rbf_gemm(
    const bf16_t* __restrict__ A,   // [4096][512] bf16  (feat)
    const bf16_t* __restrict__ Bw,  // [10112][512] bf16 (weights, padded)
    const float* __restrict__ f2g, const float* __restrict__ w2g,
    float* __restrict__ out) {
  __shared__ bf16_t At[128 * 32];
  __shared__ bf16_t Bt[128 * 32];
  __shared__ float f2s[128];
  __shared__ float w2s[128];

  // 1-D grid, bijective XCD swizzle (nwg = 2528 = 8*316), bm fastest
  const int bid = blockIdx.x;
  const int wg = (bid & 7) * (2528 / 8) + (bid >> 3);
  const int bm = wg & 31;   // 0..31 (M tiles)  -- fastest within XCD chunk
  const int bn = wg >> 5;   // 0..78 (N tiles)
  const int t = threadIdx.x;
  const int lane = t & 63;

  if (t < 128)
    f2s[t] = f2g[bm * 128 + t];
  else
    w2s[t - 128] = w2g[bn * 128 + (t - 128)];

  // staging addressing: 4 threads x 16B per 32-elem row; 64 rows per call
  const int sr = t >> 2;
  const int sc = (t & 3) * 8;
  const bf16_t* ga0 = A + (size_t)(bm * 128 + sr) * DDIM + sc;
  const bf16_t* ga1 = ga0 + (size_t)64 * DDIM;
  const bf16_t* gb0 = Bw + (size_t)(bn * 128 + sr) * DDIM + sc;
  const bf16_t* gb1 = gb0 + (size_t)64 * DDIM;
  bf16_t* sa = At + t * 8;  // linear: wave base + lane*16B
  bf16_t* sb = Bt + t * 8;

  const int wv = t >> 6;
  const int wm = (wv >> 1) * 64;  // feat group of this wave
  const int wn = (wv & 1) * 64;   // weight group of this wave
  const int fr = lane & 15;
  const int k8 = (lane >> 4) * 8;

  f32x4 acc[4][4];
#pragma unroll
  for (int i = 0; i < 4; ++i)
#pragma unroll
    for (int j = 0; j < 4; ++j) acc[i][j] = (f32x4){0.f, 0.f, 0.f, 0.f};

  for (int kt = 0; kt < DDIM / 32; ++kt) {
    const int k0 = kt * 32;
    gl_lds16(ga0 + k0, sa);
    gl_lds16(ga1 + k0, sa + 64 * 32);
    gl_lds16(gb0 + k0, sb);
    gl_lds16(gb1 + k0, sb + 64 * 32);
    __syncthreads();
    bf16x8 af[4], wf[4];
#pragma unroll
    for (int mi = 0; mi < 4; ++mi)
      af[mi] = *(const bf16x8*)(At + (wm + mi * 16 + fr) * 32 + k8);
#pragma unroll
    for (int ni = 0; ni < 4; ++ni)
      wf[ni] = *(const bf16x8*)(Bt + (wn + ni * 16 + fr) * 32 + k8);
#pragma unroll
    for (int mi = 0; mi < 4; ++mi)
#pragma unroll
      for (int ni = 0; ni < 4; ++ni)
        acc[mi][ni] = __builtin_amdgcn_mfma_f32_16x16x32_bf16(
            wf[ni], af[mi], acc[mi][ni], 0, 0, 0);  // swapped: D = W x F^T
    __syncthreads();
  }

  // epilogue: logit = exp(-0.01 * max(f2 + w2 - 2*cross, 0)), float4 dual
  // stores. Per frag: lane's feat row m = wm+mi*16+(lane&15),
  // weight col base c0 = wn+ni*16+(lane>>4)*4, regs j = c0..c0+3.
  const size_t BC = (size_t)BDIM * CDIM;
  const int m_l = lane & 15;
  const int c_l = (lane >> 4) * 4;
#pragma unroll
  for (int mi = 0; mi < 4; ++mi) {
    const int rl = wm + mi * 16 + m_l;
    const float frow = f2s[rl];
    float* orow = out + (size_t)(bm * 128 + rl) * CDIM;
#pragma unroll
    for (int ni = 0; ni < 4; ++ni) {
      const int cl = wn + ni * 16 + c_l;
      const int gcol = bn * 128 + cl;
      if (gcol < CDIM) {  // CDIM % 16 == 0: whole float4 valid or invalid
        f32x4 st;
#pragma unroll
        for (int j = 0; j < 4; ++j) {
          float m = frow + w2s[cl + j] - 2.0f * acc[mi][ni][j];
          m = fmaxf(m, 0.0f);
          st[j] = __expf(-0.01f * m);
        }
        *(f32x4*)(orow + gcol) = st;
        *(f32x4*)(orow + BC + gcol) = st;
      }
    }
  }
}

extern "C" void kernel_launch(void* const* d_in, const int* in_sizes, int n_in,
                              void* d_out, int out_size, void* d_ws,
                              size_t ws_size, hipStream_t stream) {
  const float* feat = (const float*)d_in[0];
  // d_in[1] = label (int64) — unused by the reference math
  const float* w = (const float*)d_in[2];
  float* out = (float*)d_out;

  char* ws = (char*)d_ws;
  bf16_t* fb = (bf16_t*)ws;                        // 4096*512*2  = 4,194,304 B
  bf16_t* wb = (bf16_t*)(ws + 4194304);            // 10112*512*2 = 10,354,688 B
  float* f2 = (float*)(ws + 4194304 + 10354688);   // 16,384 B
  float* w2 = (float*)(ws + 4194304 + 10354688 + 16384);  // 40,448 B

  float* wout = out + (size_t)2 * BDIM * CDIM;  // weights passthrough segment

  prep_feat<<<BDIM, 256, 0, stream>>>(feat, fb, f2);
  prep_w<<<CPAD, 256, 0, stream>>>(w, wb, w2, wout);
  rbf_gemm<<<2528, 256, 0, stream>>>(fb, wb, f2, w2, out);
}

// Round 4
// 134.433 us; speedup vs baseline: 1.0428x; 1.0309x over previous
//
#include <hip/hip_runtime.h>
#include <hip/hip_bf16.h>
#include <stdint.h>

// Problem constants
#define BDIM 4096
#define CDIM 10000
#define DDIM 512
#define CPAD 10112  // 79 * 128, padded N so GEMM loads need no guards
#define NT 16       // K tiles (512 / 32)

typedef __bf16 bf16_t;
typedef __attribute__((ext_vector_type(2))) __bf16 bf16x2;
typedef __attribute__((ext_vector_type(8))) __bf16 bf16x8;
typedef __attribute__((ext_vector_type(2))) float f32x2;
typedef __attribute__((ext_vector_type(4))) float f32x4;

__device__ __forceinline__ void gl_lds16(const void* g, void* s) {
  // async global->LDS, 16B per lane; LDS dest = wave-uniform base + lane*16
  __builtin_amdgcn_global_load_lds(
      (const __attribute__((address_space(1))) void*)g,
      (__attribute__((address_space(3))) void*)s, 16, 0, 0);
}

// --- fused prep: rows [0,BDIM) = feat, rows [BDIM,BDIM+CPAD) = weights ---
__global__ __launch_bounds__(256) void prep(
    const float* __restrict__ feat, const float* __restrict__ w,
    bf16_t* __restrict__ fb, bf16_t* __restrict__ wb,
    float* __restrict__ f2, float* __restrict__ w2,
    float* __restrict__ wout) {
  const int b = blockIdx.x;
  const int t = threadIdx.x;
  __shared__ float red[4];
  if (b < BDIM) {
    const f32x2 v = ((const f32x2*)(feat + (size_t)b * DDIM))[t];
    bf16x2 o;
    o.x = (__bf16)v.x;
    o.y = (__bf16)v.y;
    ((bf16x2*)fb)[(size_t)b * (DDIM / 2) + t] = o;
    float ss = v.x * v.x + v.y * v.y;
#pragma unroll
    for (int off = 32; off > 0; off >>= 1) ss += __shfl_down(ss, off);
    if ((t & 63) == 0) red[t >> 6] = ss;
    __syncthreads();
    if (t == 0) f2[b] = red[0] + red[1] + red[2] + red[3];
  } else {
    const int row = b - BDIM;
    if (row < CDIM) {
      const f32x2 v = ((const f32x2*)(w + (size_t)row * DDIM))[t];
      __builtin_nontemporal_store(v, (f32x2*)(wout + (size_t)row * DDIM) + t);
      bf16x2 o;
      o.x = (__bf16)v.x;
      o.y = (__bf16)v.y;
      ((bf16x2*)wb)[(size_t)row * (DDIM / 2) + t] = o;
      float ss = v.x * v.x + v.y * v.y;
#pragma unroll
      for (int off = 32; off > 0; off >>= 1) ss += __shfl_down(ss, off);
      if ((t & 63) == 0) red[t >> 6] = ss;
      __syncthreads();
      if (t == 0) w2[row] = red[0] + red[1] + red[2] + red[3];
    } else {
      bf16x2 z;
      z.x = (__bf16)0.0f;
      z.y = (__bf16)0.0f;
      ((bf16x2*)wb)[(size_t)row * (DDIM / 2) + t] = z;
      if (t == 0) w2[row] = 0.0f;
    }
  }
}

// --- main GEMM + RBF epilogue ---
// 128x128 tile, BK=32, 4 waves (2x2), mfma(wfrag, ffrag) operand-swapped.
// 3-buffer LDS round-robin, 2-tiles-ahead prefetch, counted vmcnt(4) +
// raw s_barrier (T3/T4-lite), setprio around MFMA (T5), NT stores.
__global__ __launch_bounds__(256, 3) void rbf_gemm(
    const bf16_t* __restrict__ A,   // [4096][512] bf16  (feat)
    const bf16_t* __restrict__ Bw,  // [10112][512] bf16 (weights, padded)
    const float* __restrict__ f2g, const float* __restrict__ w2g,
    float* __restrict__ out) {
  __shared__ bf16_t At[3 * 128 * 32];
  __shared__ bf16_t Bt[3 * 128 * 32];
  __shared__ float f2s[128];
  __shared__ float w2s[128];

  // 1-D grid, bijective XCD swizzle (nwg = 2528 = 8*316), bm fastest
  const int bid = blockIdx.x;
  const int wg = (bid & 7) * (2528 / 8) + (bid >> 3);
  const int bm = wg & 31;  // 0..31 (M tiles) -- fastest within XCD chunk
  const int bn = wg >> 5;  // 0..78 (N tiles)
  const int t = threadIdx.x;
  const int lane = t & 63;

  if (t < 128)
    f2s[t] = f2g[bm * 128 + t];
  else
    w2s[t - 128] = w2g[bn * 128 + (t - 128)];

  // staging addressing: 4 threads x 16B per 32-elem row; 64 rows per call
  const int sr = t >> 2;
  const int sc = (t & 3) * 8;
  const bf16_t* ga0 = A + (size_t)(bm * 128 + sr) * DDIM + sc;
  const bf16_t* ga1 = ga0 + (size_t)64 * DDIM;
  const bf16_t* gb0 = Bw + (size_t)(bn * 128 + sr) * DDIM + sc;
  const bf16_t* gb1 = gb0 + (size_t)64 * DDIM;

  const int wv = t >> 6;
  const int wm = (wv >> 1) * 64;  // feat group of this wave
  const int wn = (wv & 1) * 64;   // weight group of this wave
  const int fr = lane & 15;
  const int k8 = (lane >> 4) * 8;

#define STAGE(boff, kt)                              \
  do {                                               \
    const int k0_ = (kt) * 32;                       \
    gl_lds16(ga0 + k0_, At + (boff) + t * 8);        \
    gl_lds16(ga1 + k0_, At + (boff) + 2048 + t * 8); \
    gl_lds16(gb0 + k0_, Bt + (boff) + t * 8);        \
    gl_lds16(gb1 + k0_, Bt + (boff) + 2048 + t * 8); \
  } while (0)

  f32x4 acc[4][4];
#pragma unroll
  for (int i = 0; i < 4; ++i)
#pragma unroll
    for (int j = 0; j < 4; ++j) acc[i][j] = (f32x4){0.f, 0.f, 0.f, 0.f};

  // prologue: tiles 0 and 1 in flight; full sync drains them + f2s/w2s
  STAGE(0, 0);
  STAGE(4096, 1);
  __syncthreads();

  int o0 = 0, o1 = 4096, o2 = 8192;
#pragma unroll
  for (int kt = 0; kt < NT; ++kt) {
    if (kt + 2 < NT) STAGE(o2, kt + 2);  // issue prefetch FIRST
    bf16x8 af[4], wf[4];
#pragma unroll
    for (int mi = 0; mi < 4; ++mi)
      af[mi] = *(const bf16x8*)(At + o0 + (wm + mi * 16 + fr) * 32 + k8);
#pragma unroll
    for (int ni = 0; ni < 4; ++ni)
      wf[ni] = *(const bf16x8*)(Bt + o0 + (wn + ni * 16 + fr) * 32 + k8);
    __builtin_amdgcn_s_setprio(1);
#pragma unroll
    for (int mi = 0; mi < 4; ++mi)
#pragma unroll
      for (int ni = 0; ni < 4; ++ni)
        acc[mi][ni] = __builtin_amdgcn_mfma_f32_16x16x32_bf16(
            wf[ni], af[mi], acc[mi][ni], 0, 0, 0);  // swapped: D = W x F^T
    __builtin_amdgcn_s_setprio(0);
    if (kt < NT - 1) {
      // tile kt+1 must have landed; tile kt+2 (4 loads) stays in flight
      if (kt + 2 < NT)
        asm volatile("s_waitcnt vmcnt(4)" ::: "memory");
      else
        asm volatile("s_waitcnt vmcnt(0)" ::: "memory");
      __builtin_amdgcn_s_barrier();
    }
    const int tmp = o0;
    o0 = o1;
    o1 = o2;
    o2 = tmp;
  }

  // epilogue: logit = exp(-0.01 * max(f2 + w2 - 2*cross, 0)), float4 dual
  // nontemporal stores (don't thrash L2 with 327 MB of streaming writes).
  const size_t BC = (size_t)BDIM * CDIM;
  const int m_l = lane & 15;
  const int c_l = (lane >> 4) * 4;
#pragma unroll
  for (int mi = 0; mi < 4; ++mi) {
    const int rl = wm + mi * 16 + m_l;
    const float frow = f2s[rl];
    float* orow = out + (size_t)(bm * 128 + rl) * CDIM;
#pragma unroll
    for (int ni = 0; ni < 4; ++ni) {
      const int cl = wn + ni * 16 + c_l;
      const int gcol = bn * 128 + cl;
      if (gcol < CDIM) {  // CDIM % 16 == 0: whole float4 valid or invalid
        f32x4 st;
#pragma unroll
        for (int j = 0; j < 4; ++j) {
          float m = frow + w2s[cl + j] - 2.0f * acc[mi][ni][j];
          m = fmaxf(m, 0.0f);
          st[j] = __expf(-0.01f * m);
        }
        __builtin_nontemporal_store(st, (f32x4*)(orow + gcol));
        __builtin_nontemporal_store(st, (f32x4*)(orow + BC + gcol));
      }
    }
  }
#undef STAGE
}

extern "C" void kernel_launch(void* const* d_in, const int* in_sizes, int n_in,
                              void* d_out, int out_size, void* d_ws,
                              size_t ws_size, hipStream_t stream) {
  const float* feat = (const float*)d_in[0];
  // d_in[1] = label (int64) — unused by the reference math
  const float* w = (const float*)d_in[2];
  float* out = (float*)d_out;

  char* ws = (char*)d_ws;
  bf16_t* fb = (bf16_t*)ws;                        // 4096*512*2  = 4,194,304 B
  bf16_t* wb = (bf16_t*)(ws + 4194304);            // 10112*512*2 = 10,354,688 B
  float* f2 = (float*)(ws + 4194304 + 10354688);   // 16,384 B
  float* w2 = (float*)(ws + 4194304 + 10354688 + 16384);  // 40,448 B

  float* wout = out + (size_t)2 * BDIM * CDIM;  // weights passthrough segment

  prep<<<BDIM + CPAD, 256, 0, stream>>>(feat, w, fb, wb, f2, w2, wout);
  rbf_gemm<<<2528, 256, 0, stream>>>(fb, wb, f2, w2, out);
}

// Round 5
// 114.957 us; speedup vs baseline: 1.2195x; 1.1694x over previous
//
#include <hip/hip_runtime.h>
#include <hip/hip_bf16.h>
#include <stdint.h>

// Problem constants
#define BDIM 4096
#define CDIM 10000
#define DDIM 512
#define CPAD 10112  // 79 * 128, padded N so GEMM loads need no guards
#define NT 16       // K tiles (512 / 32)

typedef __bf16 bf16_t;
typedef __attribute__((ext_vector_type(2))) __bf16 bf16x2;
typedef __attribute__((ext_vector_type(8))) __bf16 bf16x8;
typedef __attribute__((ext_vector_type(2))) float f32x2;
typedef __attribute__((ext_vector_type(4))) float f32x4;

__device__ __forceinline__ void gl_lds16(const void* g, void* s) {
  // async global->LDS, 16B per lane; LDS dest = wave-uniform base + lane*16
  __builtin_amdgcn_global_load_lds(
      (const __attribute__((address_space(1))) void*)g,
      (__attribute__((address_space(3))) void*)s, 16, 0, 0);
}

// --- fused prep: rows [0,BDIM) = feat, rows [BDIM,BDIM+CPAD) = weights ---
__global__ __launch_bounds__(256) void prep(
    const float* __restrict__ feat, const float* __restrict__ w,
    bf16_t* __restrict__ fb, bf16_t* __restrict__ wb,
    float* __restrict__ f2, float* __restrict__ w2,
    float* __restrict__ wout) {
  const int b = blockIdx.x;
  const int t = threadIdx.x;
  __shared__ float red[4];
  if (b < BDIM) {
    const f32x2 v = ((const f32x2*)(feat + (size_t)b * DDIM))[t];
    bf16x2 o;
    o.x = (__bf16)v.x;
    o.y = (__bf16)v.y;
    ((bf16x2*)fb)[(size_t)b * (DDIM / 2) + t] = o;
    float ss = v.x * v.x + v.y * v.y;
#pragma unroll
    for (int off = 32; off > 0; off >>= 1) ss += __shfl_down(ss, off);
    if ((t & 63) == 0) red[t >> 6] = ss;
    __syncthreads();
    if (t == 0) f2[b] = red[0] + red[1] + red[2] + red[3];
  } else {
    const int row = b - BDIM;
    if (row < CDIM) {
      const f32x2 v = ((const f32x2*)(w + (size_t)row * DDIM))[t];
      __builtin_nontemporal_store(v, (f32x2*)(wout + (size_t)row * DDIM) + t);
      bf16x2 o;
      o.x = (__bf16)v.x;
      o.y = (__bf16)v.y;
      ((bf16x2*)wb)[(size_t)row * (DDIM / 2) + t] = o;
      float ss = v.x * v.x + v.y * v.y;
#pragma unroll
      for (int off = 32; off > 0; off >>= 1) ss += __shfl_down(ss, off);
      if ((t & 63) == 0) red[t >> 6] = ss;
      __syncthreads();
      if (t == 0) w2[row] = red[0] + red[1] + red[2] + red[3];
    } else {
      bf16x2 z;
      z.x = (__bf16)0.0f;
      z.y = (__bf16)0.0f;
      ((bf16x2*)wb)[(size_t)row * (DDIM / 2) + t] = z;
      if (t == 0) w2[row] = 0.0f;
    }
  }
}

// --- main GEMM + RBF epilogue ---
// 128x128 tile, BK=32, 4 waves (2x2), mfma(wfrag, ffrag) operand-swapped.
// 3-buffer LDS round-robin, counted vmcnt(4), setprio (unchanged from R4).
// NEW: LDS-staged coalesced epilogue — reshuffle through a 64x132 fp32 tile
// (reusing dead staging LDS) so every NT store is 512 B-contiguous per row
// (full 128 B lines) instead of 16 scattered 64 B segments per instruction.
__global__ __launch_bounds__(256, 3) void rbf_gemm(
    const bf16_t* __restrict__ A,   // [4096][512] bf16  (feat)
    const bf16_t* __restrict__ Bw,  // [10112][512] bf16 (weights, padded)
    const float* __restrict__ f2g, const float* __restrict__ w2g,
    float* __restrict__ out) {
  __shared__ __align__(16) char pool[49152];  // At(24576) | Bt(24576)
  bf16_t* At = (bf16_t*)pool;
  bf16_t* Bt = (bf16_t*)(pool + 24576);
  __shared__ float f2s[128];
  __shared__ float w2s[128];

  // 1-D grid, bijective XCD swizzle (nwg = 2528 = 8*316), bm fastest
  const int bid = blockIdx.x;
  const int wg = (bid & 7) * (2528 / 8) + (bid >> 3);
  const int bm = wg & 31;  // 0..31 (M tiles) -- fastest within XCD chunk
  const int bn = wg >> 5;  // 0..78 (N tiles)
  const int t = threadIdx.x;
  const int lane = t & 63;

  if (t < 128)
    f2s[t] = f2g[bm * 128 + t];
  else
    w2s[t - 128] = w2g[bn * 128 + (t - 128)];

  // staging addressing: 4 threads x 16B per 32-elem row; 64 rows per call
  const int sr = t >> 2;
  const int sc = (t & 3) * 8;
  const bf16_t* ga0 = A + (size_t)(bm * 128 + sr) * DDIM + sc;
  const bf16_t* ga1 = ga0 + (size_t)64 * DDIM;
  const bf16_t* gb0 = Bw + (size_t)(bn * 128 + sr) * DDIM + sc;
  const bf16_t* gb1 = gb0 + (size_t)64 * DDIM;

  const int wv = t >> 6;
  const int wm = (wv >> 1) * 64;  // feat group of this wave
  const int wn = (wv & 1) * 64;   // weight group of this wave
  const int fr = lane & 15;
  const int k8 = (lane >> 4) * 8;

#define STAGE(boff, kt)                              \
  do {                                               \
    const int k0_ = (kt) * 32;                       \
    gl_lds16(ga0 + k0_, At + (boff) + t * 8);        \
    gl_lds16(ga1 + k0_, At + (boff) + 2048 + t * 8); \
    gl_lds16(gb0 + k0_, Bt + (boff) + t * 8);        \
    gl_lds16(gb1 + k0_, Bt + (boff) + 2048 + t * 8); \
  } while (0)

  f32x4 acc[4][4];
#pragma unroll
  for (int i = 0; i < 4; ++i)
#pragma unroll
    for (int j = 0; j < 4; ++j) acc[i][j] = (f32x4){0.f, 0.f, 0.f, 0.f};

  // prologue: tiles 0 and 1 in flight; full sync drains them + f2s/w2s
  STAGE(0, 0);
  STAGE(4096, 1);
  __syncthreads();

  int o0 = 0, o1 = 4096, o2 = 8192;
#pragma unroll
  for (int kt = 0; kt < NT; ++kt) {
    if (kt + 2 < NT) STAGE(o2, kt + 2);  // issue prefetch FIRST
    bf16x8 af[4], wf[4];
#pragma unroll
    for (int mi = 0; mi < 4; ++mi)
      af[mi] = *(const bf16x8*)(At + o0 + (wm + mi * 16 + fr) * 32 + k8);
#pragma unroll
    for (int ni = 0; ni < 4; ++ni)
      wf[ni] = *(const bf16x8*)(Bt + o0 + (wn + ni * 16 + fr) * 32 + k8);
    __builtin_amdgcn_s_setprio(1);
#pragma unroll
    for (int mi = 0; mi < 4; ++mi)
#pragma unroll
      for (int ni = 0; ni < 4; ++ni)
        acc[mi][ni] = __builtin_amdgcn_mfma_f32_16x16x32_bf16(
            wf[ni], af[mi], acc[mi][ni], 0, 0, 0);  // swapped: D = W x F^T
    __builtin_amdgcn_s_setprio(0);
    if (kt < NT - 1) {
      // tile kt+1 must have landed; tile kt+2 (4 loads) stays in flight
      if (kt + 2 < NT)
        asm volatile("s_waitcnt vmcnt(4)" ::: "memory");
      else
        asm volatile("s_waitcnt vmcnt(0)" ::: "memory");
      __builtin_amdgcn_s_barrier();
    }
    const int tmp = o0;
    o0 = o1;
    o1 = o2;
    o2 = tmp;
  }

  __syncthreads();  // staging LDS now dead -> reuse as reshuffle tile

  // Coalesced epilogue. resh = 64 rows x 132 floats (pad: 2-way bank alias
  // only). Pass p covers output rows [p*64, p*64+64), produced by the two
  // waves with wm == p*64.
  float* resh = (float*)pool;  // 64*132*4 = 33792 B < 49152 B
  const size_t BC = (size_t)BDIM * CDIM;
  const int m_l = lane & 15;
  const int c_l = (lane >> 4) * 4;

  for (int p = 0; p < 2; ++p) {
    if ((wv >> 1) == p) {
#pragma unroll
      for (int mi = 0; mi < 4; ++mi) {
        const int rl = mi * 16 + m_l;  // row within this 64-row half
        const float frow = f2s[wm + rl];
#pragma unroll
        for (int ni = 0; ni < 4; ++ni) {
          const int cl = wn + ni * 16 + c_l;
          f32x4 st;
#pragma unroll
          for (int j = 0; j < 4; ++j) {
            float m = frow + w2s[cl + j] - 2.0f * acc[mi][ni][j];
            m = fmaxf(m, 0.0f);
            st[j] = __expf(-0.01f * m);
          }
          *(f32x4*)(resh + rl * 132 + cl) = st;
        }
      }
    }
    __syncthreads();
    // stream 64 rows x 128 cols: 32 lanes x float4 = 512 B contiguous/row
    {
      const int rr = t >> 5;         // 0..7
      const int cc = (t & 31) * 4;   // 0..124
      const int gcol = bn * 128 + cc;
      if (gcol < CDIM) {
#pragma unroll
        for (int it = 0; it < 8; ++it) {
          const int r = it * 8 + rr;
          const f32x4 v = *(const f32x4*)(resh + r * 132 + cc);
          float* orow = out + (size_t)(bm * 128 + p * 64 + r) * CDIM + gcol;
          __builtin_nontemporal_store(v, (f32x4*)orow);
          __builtin_nontemporal_store(v, (f32x4*)(orow + BC));
        }
      }
    }
    __syncthreads();  // readers done before next pass overwrites resh
  }
#undef STAGE
}

extern "C" void kernel_launch(void* const* d_in, const int* in_sizes, int n_in,
                              void* d_out, int out_size, void* d_ws,
                              size_t ws_size, hipStream_t stream) {
  const float* feat = (const float*)d_in[0];
  // d_in[1] = label (int64) — unused by the reference math
  const float* w = (const float*)d_in[2];
  float* out = (float*)d_out;

  char* ws = (char*)d_ws;
  bf16_t* fb = (bf16_t*)ws;                        // 4096*512*2  = 4,194,304 B
  bf16_t* wb = (bf16_t*)(ws + 4194304);            // 10112*512*2 = 10,354,688 B
  float* f2 = (float*)(ws + 4194304 + 10354688);   // 16,384 B
  float* w2 = (float*)(ws + 4194304 + 10354688 + 16384);  // 40,448 B

  float* wout = out + (size_t)2 * BDIM * CDIM;  // weights passthrough segment

  prep<<<BDIM + CPAD, 256, 0, stream>>>(feat, w, fb, wb, f2, w2, wout);
  rbf_gemm<<<2528, 256, 0, stream>>>(fb, wb, f2, w2, out);
}